// Round 1
// baseline (1671.172 us; speedup 1.0000x reference)
//
#include <hip/hip_runtime.h>
#include <math.h>

// DN test-mode forward:
//   ny[y]   = ||x2y_w[y,:]||                    (Y=32768 rows, X=4096)
//   nz[z]   = ||y2z_w[z,:]||                    (Z=1000 rows, Y=32768)
//   s[b,y]  = x[b,:] . x2y_w[y,:]               (xf normalization is a positive
//                                                per-b scale -> argmax invariant)
//   winner[b] = argmax_y (age[y]>=1 ? s/ny : 0) (first-index tie-break, matches jnp.argmax)
//   out[b,z]  = y2z_w[z,winner[b]] / max(nz[z],1e-12)

#define BM 128
#define BN 128
#define BK 16
#define PAD 4

__global__ __launch_bounds__(256) void row_norms(const float* __restrict__ src,
                                                 float* __restrict__ dst,
                                                 int cols) {
    const int r = blockIdx.x;
    const float* row = src + (size_t)r * cols;
    const int t = threadIdx.x;
    float s = 0.f;
    const int nIter = cols >> 10;  // cols / (256 threads * 4 floats)
    for (int i = 0; i < nIter; ++i) {
        const float4 v = *reinterpret_cast<const float4*>(row + (((i << 8) + t) << 2));
        s = fmaf(v.x, v.x, s); s = fmaf(v.y, v.y, s);
        s = fmaf(v.z, v.z, s); s = fmaf(v.w, v.w, s);
    }
    #pragma unroll
    for (int off = 32; off; off >>= 1) s += __shfl_down(s, off);
    __shared__ float red[4];
    if ((t & 63) == 0) red[t >> 6] = s;
    __syncthreads();
    if (t == 0) dst[r] = sqrtf(red[0] + red[1] + red[2] + red[3]);
}

// C = x . W^T over K=4096, fused with gated per-row argmax over this block's BN columns.
__global__ __launch_bounds__(256) void gemm_argmax(
    const float* __restrict__ x,      // [512][4096]
    const float* __restrict__ w,      // [32768][4096]
    const float* __restrict__ ny,     // [32768]
    const int*  __restrict__ age,     // [32768]
    float2* __restrict__ cand,        // [512][nChunks] (val, idx-bits)
    int nChunks)
{
    __shared__ __align__(16) float As[BK][BM + PAD];
    __shared__ __align__(16) float Bs[BK][BN + PAD];
    const int b0 = blockIdx.x * BM;
    const int y0 = blockIdx.y * BN;
    const int tid = threadIdx.x;
    const int tm = tid >> 4, tn = tid & 15;

    float acc[8][8];
    #pragma unroll
    for (int i = 0; i < 8; ++i)
        #pragma unroll
        for (int j = 0; j < 8; ++j) acc[i][j] = 0.f;

    for (int k0 = 0; k0 < 4096; k0 += BK) {
        #pragma unroll
        for (int i = 0; i < 2; ++i) {
            const int lid = i * 256 + tid;   // 0..511
            const int row = lid >> 2;        // 0..127
            const int c4  = lid & 3;         // float4 slot within the BK=16 row chunk
            const float4 va = *reinterpret_cast<const float4*>(
                x + (size_t)(b0 + row) * 4096 + k0 + (c4 << 2));
            As[c4 * 4 + 0][row] = va.x; As[c4 * 4 + 1][row] = va.y;
            As[c4 * 4 + 2][row] = va.z; As[c4 * 4 + 3][row] = va.w;
            const float4 vb = *reinterpret_cast<const float4*>(
                w + (size_t)(y0 + row) * 4096 + k0 + (c4 << 2));
            Bs[c4 * 4 + 0][row] = vb.x; Bs[c4 * 4 + 1][row] = vb.y;
            Bs[c4 * 4 + 2][row] = vb.z; Bs[c4 * 4 + 3][row] = vb.w;
        }
        __syncthreads();
        #pragma unroll
        for (int k = 0; k < BK; ++k) {
            const float4* ar = reinterpret_cast<const float4*>(&As[k][tm * 8]);
            const float4* br = reinterpret_cast<const float4*>(&Bs[k][tn * 8]);
            const float4 a0 = ar[0], a1 = ar[1];
            const float4 b0f = br[0], b1f = br[1];
            const float a[8] = {a0.x, a0.y, a0.z, a0.w, a1.x, a1.y, a1.z, a1.w};
            const float bb[8] = {b0f.x, b0f.y, b0f.z, b0f.w, b1f.x, b1f.y, b1f.z, b1f.w};
            #pragma unroll
            for (int i = 0; i < 8; ++i)
                #pragma unroll
                for (int j = 0; j < 8; ++j)
                    acc[i][j] = fmaf(a[i], bb[j], acc[i][j]);
        }
        __syncthreads();
    }

    // Epilogue: gate + scale, argmax over this tile's 128 y's per b-row.
    float scale[8]; int act[8]; int yj[8];
    #pragma unroll
    for (int j = 0; j < 8; ++j) {
        yj[j] = y0 + tn * 8 + j;
        scale[j] = 1.0f / fmaxf(ny[yj[j]], 1e-12f);
        act[j] = age[yj[j]] >= 1;
    }
    #pragma unroll
    for (int i = 0; i < 8; ++i) {
        float bv = -INFINITY; int bi = 0x7fffffff;
        #pragma unroll
        for (int j = 0; j < 8; ++j) {
            const float v = act[j] ? acc[i][j] * scale[j] : 0.0f;
            if (v > bv) { bv = v; bi = yj[j]; }   // ascending j keeps lowest idx on ties
        }
        #pragma unroll
        for (int off = 8; off; off >>= 1) {       // reduce across tn (16-lane groups)
            const float ov = __shfl_xor(bv, off);
            const int   oi = __shfl_xor(bi, off);
            if (ov > bv || (ov == bv && oi < bi)) { bv = ov; bi = oi; }
        }
        if (tn == 0)
            cand[(size_t)(b0 + tm * 8 + i) * nChunks + blockIdx.y] =
                make_float2(bv, __int_as_float(bi));
    }
}

__global__ __launch_bounds__(256) void reduce_winner(const float2* __restrict__ cand,
                                                     int* __restrict__ winner,
                                                     int nChunks) {
    const int b = blockIdx.x;
    const int t = threadIdx.x;
    float bv = -INFINITY; int bi = 0x7fffffff;
    for (int c = t; c < nChunks; c += 256) {
        const float2 e = cand[(size_t)b * nChunks + c];
        const int i = __float_as_int(e.y);
        if (e.x > bv || (e.x == bv && i < bi)) { bv = e.x; bi = i; }
    }
    #pragma unroll
    for (int off = 32; off; off >>= 1) {
        const float ov = __shfl_xor(bv, off);
        const int   oi = __shfl_xor(bi, off);
        if (ov > bv || (ov == bv && oi < bi)) { bv = ov; bi = oi; }
    }
    __shared__ float sv[4]; __shared__ int si[4];
    if ((t & 63) == 0) { sv[t >> 6] = bv; si[t >> 6] = bi; }
    __syncthreads();
    if (t == 0) {
        #pragma unroll
        for (int wv = 1; wv < 4; ++wv)
            if (sv[wv] > bv || (sv[wv] == bv && si[wv] < bi)) { bv = sv[wv]; bi = si[wv]; }
        winner[b] = bi;
    }
}

__global__ __launch_bounds__(256) void gather_out(const float* __restrict__ y2z,
                                                  const float* __restrict__ nz,
                                                  const int* __restrict__ winner,
                                                  float* __restrict__ out,
                                                  int B, int Z, int Y) {
    const int g = blockIdx.x * 256 + threadIdx.x;
    if (g >= B * Z) return;
    const int b = g / Z, z = g - b * Z;
    out[g] = y2z[(size_t)z * Y + winner[b]] / fmaxf(nz[z], 1e-12f);
}

extern "C" void kernel_launch(void* const* d_in, const int* in_sizes, int n_in,
                              void* d_out, int out_size, void* d_ws, size_t ws_size,
                              hipStream_t stream) {
    const float* x     = (const float*)d_in[0];
    // d_in[1] = z (unused in test-mode forward)
    const float* x2y_w = (const float*)d_in[2];
    const float* y2z_w = (const float*)d_in[3];
    const int*   y_age = (const int*)d_in[4];
    float* out = (float*)d_out;

    const int B = 512, X = 4096, Y = 32768, Z = 1000;
    const int nChunks = Y / BN;  // 256

    float*  ny     = (float*)d_ws;                       // 32768 floats
    float*  nz     = ny + Y;                             // 1000 (padded to 1024)
    float2* cand   = (float2*)(nz + 1024);               // 512*256 float2 = 1 MB
    int*    winner = (int*)(cand + (size_t)B * nChunks); // 512 ints

    row_norms<<<Y, 256, 0, stream>>>(x2y_w, ny, X);
    row_norms<<<Z, 256, 0, stream>>>(y2z_w, nz, Y);

    dim3 grid(B / BM, Y / BN);
    gemm_argmax<<<grid, 256, 0, stream>>>(x, x2y_w, ny, y_age, cand, nChunks);
    reduce_winner<<<B, 256, 0, stream>>>(cand, winner, nChunks);
    gather_out<<<(B * Z + 255) / 256, 256, 0, stream>>>(y2z_w, nz, winner, out, B, Z, Y);
}

// Round 2
// 626.245 us; speedup vs baseline: 2.6686x; 2.6686x over previous
//
#include <hip/hip_runtime.h>
#include <math.h>

// DN test-mode forward via split-bf16 MFMA:
//   s[b,y] = x[b,:].x2y_w[y,:]  computed as  hi*hi + hi*lo + lo*hi  (bf16 MFMA, f32 acc)
//   winner[b] = argmax_y (age[y]>=1 ? s/||w_y|| : 0), first-index ties
//   out[b,z]  = y2z_w[z,winner[b]] / max(||y2z_w[z,:]||, 1e-12)

typedef __attribute__((ext_vector_type(8))) short short8;
typedef __attribute__((ext_vector_type(4))) float f32x4;

#define NT 128  // K tile-groups of 32 f32 columns

__device__ __forceinline__ unsigned bf16rtn(float f) {
    unsigned u = __float_as_uint(f);
    return (u + 0x7fffu + ((u >> 16) & 1u)) >> 16;
}
__device__ __forceinline__ void split2(float f0, float f1, unsigned& hw, unsigned& lw) {
    unsigned h0 = bf16rtn(f0), h1 = bf16rtn(f1);
    float r0 = f0 - __uint_as_float(h0 << 16);   // exact (Sterbenz)
    float r1 = f1 - __uint_as_float(h1 << 16);
    hw = h0 | (h1 << 16);
    lw = bf16rtn(r0) | (bf16rtn(r1) << 16);
}
__device__ __forceinline__ void cvt8(const float4& a, const float4& b, uint4& hi, uint4& lo) {
    split2(a.x, a.y, hi.x, lo.x);
    split2(a.z, a.w, hi.y, lo.y);
    split2(b.x, b.y, hi.z, lo.z);
    split2(b.z, b.w, hi.w, lo.w);
}

struct Stage { float4 a00, a01, a10, a11, b0, b1; };

__global__ __launch_bounds__(256) void row_norms(const float* __restrict__ src,
                                                 float* __restrict__ dst, int cols) {
    const int r = blockIdx.x;
    const float* row = src + (size_t)r * cols;
    const int t = threadIdx.x;
    float s = 0.f;
    const int nIter = cols >> 10;
    for (int i = 0; i < nIter; ++i) {
        const float4 v = *reinterpret_cast<const float4*>(row + (((i << 8) + t) << 2));
        s = fmaf(v.x, v.x, s); s = fmaf(v.y, v.y, s);
        s = fmaf(v.z, v.z, s); s = fmaf(v.w, v.w, s);
    }
    #pragma unroll
    for (int off = 32; off; off >>= 1) s += __shfl_down(s, off);
    __shared__ float red[4];
    if ((t & 63) == 0) red[t >> 6] = s;
    __syncthreads();
    if (t == 0) dst[r] = sqrtf(red[0] + red[1] + red[2] + red[3]);
}

__global__ __launch_bounds__(512, 2) void gemm_argmax(
    const float* __restrict__ x,    // [512][4096]
    const float* __restrict__ w,    // [32768][4096]
    const float* __restrict__ ny,   // [32768]
    const int*  __restrict__ age,   // [32768]
    float2* __restrict__ cand)      // [512][256]
{
    __shared__ uint4 AsHi[2][1024];   // [buf][256 rows * 4 slots] (16B slots, swizzled)
    __shared__ uint4 AsLo[2][1024];
    __shared__ uint4 BsHi[2][512];    // [buf][128 rows * 4 slots]
    __shared__ uint4 BsLo[2][512];
    __shared__ float2 comb[256][2];

    const int tid = threadIdx.x;
    const int b0 = blockIdx.x << 8;   // BM=256
    const int y0 = blockIdx.y << 7;   // BN=128

    // ---- staging coords (8 f32 = one 16B bf16 slot per (row,slot) id) ----
    const int sA = tid & 3;                 // slot 0..3 (8 f32 each)
    const int rA0 = tid >> 2;               // rows 0..127 (i=0), +128 (i=1)
    const int rA1 = rA0 + 128;
    const int wiA0 = (rA0 << 2) + (sA ^ ((rA0 >> 1) & 3));
    const int wiA1 = (rA1 << 2) + (sA ^ ((rA1 >> 1) & 3));
    const int rB = tid >> 2;                // 0..127
    const int wiB = (rB << 2) + (sA ^ ((rB >> 1) & 3));

    const float* aP0 = x + (size_t)(b0 + rA0) * 4096 + (sA << 3);
    const float* aP1 = x + (size_t)(b0 + rA1) * 4096 + (sA << 3);
    const float* bP  = w + (size_t)(y0 + rB) * 4096 + (sA << 3);

#define LOADT(R, t) do { const int k0_ = (t) << 5; \
    R.a00 = *(const float4*)(aP0 + k0_);  R.a01 = *(const float4*)(aP0 + k0_ + 4); \
    R.a10 = *(const float4*)(aP1 + k0_);  R.a11 = *(const float4*)(aP1 + k0_ + 4); \
    R.b0  = *(const float4*)(bP  + k0_);  R.b1  = *(const float4*)(bP  + k0_ + 4); } while (0)

#define STORET(buf, R) do { uint4 h_, l_; \
    cvt8(R.a00, R.a01, h_, l_); AsHi[buf][wiA0] = h_; AsLo[buf][wiA0] = l_; \
    cvt8(R.a10, R.a11, h_, l_); AsHi[buf][wiA1] = h_; AsLo[buf][wiA1] = l_; \
    cvt8(R.b0,  R.b1,  h_, l_); BsHi[buf][wiB]  = h_; BsLo[buf][wiB]  = l_; } while (0)

    // ---- MFMA lane decomposition ----
    const int lane = tid & 63, wave = tid >> 6;
    const int wm = wave >> 1, wn = wave & 1;     // 4 M-waves x 2 N-waves
    const int rl = lane & 15, kg = lane >> 4;
    const int swz = (rl >> 1) & 3;
    const int aBase = (((wm << 6) + rl) << 2) + (kg ^ swz);  // + mi*64
    const int bBase = (((wn << 6) + rl) << 2) + (kg ^ swz);  // + ni*64

    f32x4 acc[4][4];
    #pragma unroll
    for (int mi = 0; mi < 4; ++mi)
        #pragma unroll
        for (int ni = 0; ni < 4; ++ni)
            acc[mi][ni] = (f32x4)0.0f;

#define PAIR(AT, BT) do { \
    short8 af_[4], bf_[4]; \
    _Pragma("unroll") for (int mi = 0; mi < 4; ++mi) \
        af_[mi] = *(const short8*)&AT[aBase + (mi << 6)]; \
    _Pragma("unroll") for (int ni = 0; ni < 4; ++ni) \
        bf_[ni] = *(const short8*)&BT[bBase + (ni << 6)]; \
    _Pragma("unroll") for (int mi = 0; mi < 4; ++mi) \
        _Pragma("unroll") for (int ni = 0; ni < 4; ++ni) \
            acc[mi][ni] = __builtin_amdgcn_mfma_f32_16x16x32_bf16(af_[mi], bf_[ni], acc[mi][ni], 0, 0, 0); \
} while (0)

#define COMPUTE(buf) do { \
    PAIR(AsHi[buf], BsHi[buf]); \
    PAIR(AsHi[buf], BsLo[buf]); \
    PAIR(AsLo[buf], BsHi[buf]); } while (0)

    Stage P, Q;
    LOADT(P, 0);
    STORET(0, P);
    LOADT(P, 1);
    __syncthreads();

    for (int t = 0; t < NT; t += 2) {
        if (t + 2 < NT) LOADT(Q, t + 2);   // in flight across this whole iter
        COMPUTE(0);
        STORET(1, P);                      // tile t+1 (waits only P's loads)
        __syncthreads();
        if (t + 3 < NT) LOADT(P, t + 3);
        COMPUTE(1);
        if (t + 2 < NT) STORET(0, Q);
        __syncthreads();
    }

    // ---- epilogue: gate + scale + argmax ----
    // C/D mapping: value j of acc[mi][ni] = S[b0 + wm*64 + mi*16 + 4*kg + j][y0 + wn*64 + ni*16 + rl]
    float scl[4]; int activ[4], ybase[4];
    #pragma unroll
    for (int ni = 0; ni < 4; ++ni) {
        const int yy = y0 + (wn << 6) + (ni << 4) + rl;
        ybase[ni] = yy;
        scl[ni] = 1.0f / fmaxf(ny[yy], 1e-12f);
        activ[ni] = (age[yy] >= 1);
    }
    #pragma unroll
    for (int mi = 0; mi < 4; ++mi) {
        #pragma unroll
        for (int j = 0; j < 4; ++j) {
            float bv = -INFINITY; int bi = 0x7fffffff;
            #pragma unroll
            for (int ni = 0; ni < 4; ++ni) {   // ascending y -> first-index ties
                const float v = activ[ni] ? acc[mi][ni][j] * scl[ni] : 0.0f;
                if (v > bv) { bv = v; bi = ybase[ni]; }
            }
            #pragma unroll
            for (int off = 1; off < 16; off <<= 1) {  // reduce across rl (16-lane group)
                const float ov = __shfl_xor(bv, off);
                const int   oi = __shfl_xor(bi, off);
                if (ov > bv || (ov == bv && oi < bi)) { bv = ov; bi = oi; }
            }
            if (rl == 0)
                comb[(wm << 6) + (mi << 4) + (kg << 2) + j][wn] = make_float2(bv, __int_as_float(bi));
        }
    }
    __syncthreads();
    if (tid < 256) {
        const float2 e0 = comb[tid][0], e1 = comb[tid][1];
        const int i0 = __float_as_int(e0.y), i1 = __float_as_int(e1.y);
        const bool take1 = (e1.x > e0.x) || (e1.x == e0.x && i1 < i0);
        cand[(size_t)(b0 + tid) * 256 + blockIdx.y] = take1 ? e1 : e0;
    }
#undef LOADT
#undef STORET
#undef PAIR
#undef COMPUTE
}

__global__ __launch_bounds__(256) void reduce_winner(const float2* __restrict__ cand,
                                                     int* __restrict__ winner, int nChunks) {
    const int b = blockIdx.x;
    const int t = threadIdx.x;
    float bv = -INFINITY; int bi = 0x7fffffff;
    for (int c = t; c < nChunks; c += 256) {
        const float2 e = cand[(size_t)b * nChunks + c];
        const int i = __float_as_int(e.y);
        if (e.x > bv || (e.x == bv && i < bi)) { bv = e.x; bi = i; }
    }
    #pragma unroll
    for (int off = 32; off; off >>= 1) {
        const float ov = __shfl_xor(bv, off);
        const int   oi = __shfl_xor(bi, off);
        if (ov > bv || (ov == bv && oi < bi)) { bv = ov; bi = oi; }
    }
    __shared__ float sv[4]; __shared__ int si[4];
    if ((t & 63) == 0) { sv[t >> 6] = bv; si[t >> 6] = bi; }
    __syncthreads();
    if (t == 0) {
        #pragma unroll
        for (int wv = 1; wv < 4; ++wv)
            if (sv[wv] > bv || (sv[wv] == bv && si[wv] < bi)) { bv = sv[wv]; bi = si[wv]; }
        winner[b] = bi;
    }
}

__global__ __launch_bounds__(256) void gather_out(const float* __restrict__ y2z,
                                                  const float* __restrict__ nz,
                                                  const int* __restrict__ winner,
                                                  float* __restrict__ out,
                                                  int B, int Z, int Y) {
    const int g = blockIdx.x * 256 + threadIdx.x;
    if (g >= B * Z) return;
    const int b = g / Z, z = g - b * Z;
    out[g] = y2z[(size_t)z * Y + winner[b]] / fmaxf(nz[z], 1e-12f);
}

extern "C" void kernel_launch(void* const* d_in, const int* in_sizes, int n_in,
                              void* d_out, int out_size, void* d_ws, size_t ws_size,
                              hipStream_t stream) {
    const float* x     = (const float*)d_in[0];
    const float* x2y_w = (const float*)d_in[2];
    const float* y2z_w = (const float*)d_in[3];
    const int*   y_age = (const int*)d_in[4];
    float* out = (float*)d_out;

    const int B = 512, X = 4096, Y = 32768, Z = 1000;
    const int nChunks = 256;

    float*  ny     = (float*)d_ws;                       // 32768 f32
    float*  nz     = ny + Y;                             // 1024 f32 (1000 used)
    float2* cand   = (float2*)(nz + 1024);               // 512*256 float2 = 1 MB
    int*    winner = (int*)(cand + (size_t)B * nChunks); // 512 ints

    row_norms<<<Y, 256, 0, stream>>>(x2y_w, ny, X);
    row_norms<<<Z, 256, 0, stream>>>(y2z_w, nz, Y);

    gemm_argmax<<<dim3(2, 256), 512, 0, stream>>>(x, x2y_w, ny, y_age, cand);
    reduce_winner<<<B, 256, 0, stream>>>(cand, winner, nChunks);
    gather_out<<<(B * Z + 255) / 256, 256, 0, stream>>>(y2z_w, nz, winner, out, B, Z, Y);
}